// Round 1
// baseline (1748.861 us; speedup 1.0000x reference)
//
#include <hip/hip_runtime.h>
#include <hip/hip_bf16.h>
#include <math.h>

#define NFM 512   // NFMODES
#define NE  256
#define NUN 32    // NUNPAIRED
#define NM  480   // NMODES = NFM - NUN
#define NB  32    // BATCH
#define NF  288   // NE + NUN  (Ffull dim)

// ---------------- Ja = (J - J^T)/2 ----------------
__global__ __launch_bounds__(256)
void build_ja_k(const float* __restrict__ J, float* __restrict__ Ja) {
  int t = blockIdx.x * blockDim.x + threadIdx.x;
  int stride = gridDim.x * blockDim.x;
  for (int e = t; e < NM * NM; e += stride) {
    int i = e / NM, j = e - i * NM;
    Ja[e] = 0.5f * (J[i * NM + j] - J[j * NM + i]);
  }
}

// ---------------- Tmp[b] (256x480) = Up_b (256x480) @ Ja (480x480) ----------
// BM=BN=64, BK=16, 256 threads, 4x4 per thread.
__global__ __launch_bounds__(256)
void gemm1_k(const float* __restrict__ U, const int* __restrict__ idx,
             const float* __restrict__ Ja, float* __restrict__ Tmp) {
  const int b  = blockIdx.z;
  const int m0 = blockIdx.y << 6;
  const int n0 = blockIdx.x << 6;
  const int tid = threadIdx.x;
  __shared__ float As[16][64];
  __shared__ float Bs[16][64];
  const int ar = tid >> 2, ac = (tid & 3) << 2;   // A tile: row 0..63, col 0,4,8,12
  const int br = tid >> 4, bc = (tid & 15) << 2;  // B tile: row(k) 0..15, col 0..60
  const int tx = tid & 15, ty = tid >> 4;
  const float* Arow = U + (size_t)idx[b * NE + m0 + ar] * NFM + NUN;
  float acc[4][4] = {};
  for (int l0 = 0; l0 < NM; l0 += 16) {
    float4 av = *(const float4*)(Arow + l0 + ac);
    As[ac + 0][ar] = av.x; As[ac + 1][ar] = av.y;
    As[ac + 2][ar] = av.z; As[ac + 3][ar] = av.w;
    float4 bv = make_float4(0.f, 0.f, 0.f, 0.f);
    if (n0 + bc < NM) bv = *(const float4*)(Ja + (size_t)(l0 + br) * NM + n0 + bc);
    *(float4*)(&Bs[br][bc]) = bv;
    __syncthreads();
#pragma unroll
    for (int kk = 0; kk < 16; ++kk) {
      float4 a4 = *(const float4*)(&As[kk][ty << 2]);
      float4 b4 = *(const float4*)(&Bs[kk][tx << 2]);
      float a[4] = {a4.x, a4.y, a4.z, a4.w};
      float bb[4] = {b4.x, b4.y, b4.z, b4.w};
#pragma unroll
      for (int q = 0; q < 4; ++q)
#pragma unroll
        for (int p = 0; p < 4; ++p) acc[q][p] = fmaf(a[q], bb[p], acc[q][p]);
    }
    __syncthreads();
  }
  float* Tb = Tmp + (size_t)b * NE * NM;
#pragma unroll
  for (int q = 0; q < 4; ++q) {
    int r = m0 + (ty << 2) + q;
#pragma unroll
    for (int p = 0; p < 4; ++p) {
      int m = n0 + (tx << 2) + p;
      if (m < NM) Tb[(size_t)r * NM + m] = acc[q][p];
    }
  }
}

// ---------------- F[b] (256x256) = Tmp[b] (256x480) @ Up_b^T ----------------
// writes into Ffull[b][0:256][0:256] (stride NF)
__global__ __launch_bounds__(256)
void gemm2_k(const float* __restrict__ U, const int* __restrict__ idx,
             const float* __restrict__ Tmp, float* __restrict__ Ff) {
  const int b  = blockIdx.z;
  const int m0 = blockIdx.y << 6;
  const int n0 = blockIdx.x << 6;
  const int tid = threadIdx.x;
  __shared__ float As[16][64];
  __shared__ float Bs[16][64];
  const int ar = tid >> 2, ac = (tid & 3) << 2;   // A: row 0..63, k-col 0,4,8,12
  const int jr = tid >> 2, kc = (tid & 3) << 2;   // B: col j 0..63, k 0,4,8,12
  const int tx = tid & 15, ty = tid >> 4;
  const float* Arow = Tmp + ((size_t)b * NE + m0 + ar) * NM;
  const float* Brow = U + (size_t)idx[b * NE + n0 + jr] * NFM + NUN;
  float acc[4][4] = {};
  for (int l0 = 0; l0 < NM; l0 += 16) {
    float4 av = *(const float4*)(Arow + l0 + ac);
    As[ac + 0][ar] = av.x; As[ac + 1][ar] = av.y;
    As[ac + 2][ar] = av.z; As[ac + 3][ar] = av.w;
    float4 bv = *(const float4*)(Brow + l0 + kc);
    Bs[kc + 0][jr] = bv.x; Bs[kc + 1][jr] = bv.y;
    Bs[kc + 2][jr] = bv.z; Bs[kc + 3][jr] = bv.w;
    __syncthreads();
#pragma unroll
    for (int kk = 0; kk < 16; ++kk) {
      float4 a4 = *(const float4*)(&As[kk][ty << 2]);
      float4 b4 = *(const float4*)(&Bs[kk][tx << 2]);
      float a[4] = {a4.x, a4.y, a4.z, a4.w};
      float bb[4] = {b4.x, b4.y, b4.z, b4.w};
#pragma unroll
      for (int q = 0; q < 4; ++q)
#pragma unroll
        for (int p = 0; p < 4; ++p) acc[q][p] = fmaf(a[q], bb[p], acc[q][p]);
    }
    __syncthreads();
  }
  float* Fb = Ff + (size_t)b * NF * NF;
#pragma unroll
  for (int q = 0; q < 4; ++q) {
    int i = m0 + (ty << 2) + q;
#pragma unroll
    for (int p = 0; p < 4; ++p) {
      int j = n0 + (tx << 2) + p;
      Fb[(size_t)i * NF + j] = acc[q][p];
    }
  }
}

// ---------------- edges: Uun block, -Uun^T block, zero corner ---------------
__global__ __launch_bounds__(256)
void fill_edges_k(const float* __restrict__ U, const int* __restrict__ idx,
                  float* __restrict__ Ff) {
  const int b = blockIdx.x;
  const int tid = threadIdx.x;  // 0..255 = row i
  float* Fb = Ff + (size_t)b * NF * NF;
  const int gr = idx[b * NE + tid];
#pragma unroll 4
  for (int u = 0; u < NUN; ++u) {
    float v = U[(size_t)gr * NFM + u];
    Fb[(size_t)tid * NF + NE + u] = v;
    Fb[(size_t)(NE + u) * NF + tid] = -v;
  }
  if (tid < NUN) {
    for (int v = 0; v < NUN; ++v) Fb[(size_t)(NE + tid) * NF + NE + v] = 0.f;
  }
}

// ---------------- Pfaffian: Parlett-Reid LTL^T with partial pivoting --------
// one block per batch matrix; A (NFxNF) in global ws
__global__ __launch_bounds__(512)
void pfaffian_k(float* __restrict__ Ff, float* __restrict__ out) {
  const int b = blockIdx.x;
  float* A = Ff + (size_t)b * NF * NF;
  const int tid = threadIdx.x;
  __shared__ float s_tau[NF];
  __shared__ float s_c[NF];
  __shared__ float s_rv[8];
  __shared__ int   s_ri[8];
  __shared__ int   s_kp;

  float sign = 1.f, logabs = 0.f;  // only thread 0's copy matters

  for (int k = 0; k < NF - 1; k += 2) {
    // ---- argmax_{i>k} |A[i][k]|  (each thread handles <=1 element) ----
    float best = -1.f;
    int bi = NF;
    {
      int i = k + 1 + tid;
      if (i < NF) { best = fabsf(A[(size_t)i * NF + k]); bi = i; }
    }
#pragma unroll
    for (int m = 32; m > 0; m >>= 1) {
      float ov = __shfl_xor(best, m, 64);
      int   oi = __shfl_xor(bi, m, 64);
      if (ov > best || (ov == best && oi < bi)) { best = ov; bi = oi; }
    }
    if ((tid & 63) == 0) { s_rv[tid >> 6] = best; s_ri[tid >> 6] = bi; }
    __syncthreads();
    if (tid == 0) {
      float bv = s_rv[0]; int bix = s_ri[0];
      for (int w = 1; w < 8; ++w) {
        if (s_rv[w] > bv || (s_rv[w] == bv && s_ri[w] < bix)) { bv = s_rv[w]; bix = s_ri[w]; }
      }
      s_kp = bix;
    }
    __syncthreads();
    const int kp = s_kp;

    // ---- swap row/col (k+1) <-> kp ----
    if (kp != k + 1) {
      for (int j = k + tid; j < NF; j += 512) {
        float t1 = A[(size_t)(k + 1) * NF + j];
        A[(size_t)(k + 1) * NF + j] = A[(size_t)kp * NF + j];
        A[(size_t)kp * NF + j] = t1;
      }
      __syncthreads();
      for (int i = k + tid; i < NF; i += 512) {
        float t1 = A[(size_t)i * NF + k + 1];
        A[(size_t)i * NF + k + 1] = A[(size_t)i * NF + kp];
        A[(size_t)i * NF + kp] = t1;
      }
      __syncthreads();
    }

    // ---- pivot + stage tau, c ----
    float piv = A[(size_t)k * NF + k + 1];  // all threads read (broadcast)
    if (tid == 0) {
      if (kp != k + 1) sign = -sign;
      if (piv < 0.f) sign = -sign;
      else if (piv == 0.f) sign = 0.f;
      logabs += logf(fabsf(piv));
    }
    float invp = 1.f / piv;
    if (tid < NF) {
      int i = tid;
      s_tau[i] = (i > k + 1) ? A[(size_t)k * NF + i] * invp : 0.f;
      s_c[i]   = (i > k + 1) ? A[(size_t)i * NF + k + 1] : 0.f;
    }
    __syncthreads();

    // ---- rank-2 trailing update: A[i][j] += tau_i*c_j - c_i*tau_j ----
    const int tx = tid & 63, ty = tid >> 6;  // 8 row groups x 64 lanes
    for (int i = k + 2 + ty; i < NF; i += 8) {
      float ti = s_tau[i], ci = s_c[i];
      for (int j = k + 2 + tx; j < NF; j += 64) {
        A[(size_t)i * NF + j] += ti * s_c[j] - ci * s_tau[j];
      }
    }
    __syncthreads();
  }

  if (tid == 0) {
    out[b] = sign;
    out[NB + b] = logabs;
  }
}

extern "C" void kernel_launch(void* const* d_in, const int* in_sizes, int n_in,
                              void* d_out, int out_size, void* d_ws, size_t ws_size,
                              hipStream_t stream) {
  const float* U  = (const float*)d_in[0];
  const float* J  = (const float*)d_in[1];
  const int* idx  = (const int*)d_in[2];
  float* out = (float*)d_out;
  float* ws = (float*)d_ws;

  float* Ja  = ws;                         // 480*480           = 230400 floats
  float* Tmp = Ja + (size_t)NM * NM;       // 32*256*480        = 3932160 floats
  float* Ff  = Tmp + (size_t)NB * NE * NM; // 32*288*288        = 2654208 floats

  build_ja_k<<<dim3(256), dim3(256), 0, stream>>>(J, Ja);
  gemm1_k<<<dim3(8, 4, NB), dim3(256), 0, stream>>>(U, idx, Ja, Tmp);
  gemm2_k<<<dim3(4, 4, NB), dim3(256), 0, stream>>>(U, idx, Tmp, Ff);
  fill_edges_k<<<dim3(NB), dim3(256), 0, stream>>>(U, idx, Ff);
  pfaffian_k<<<dim3(NB), dim3(512), 0, stream>>>(Ff, out);
}

// Round 2
// 841.862 us; speedup vs baseline: 2.0774x; 2.0774x over previous
//
#include <hip/hip_runtime.h>
#include <hip/hip_bf16.h>
#include <math.h>

#define NFM 512   // NFMODES
#define NE  256
#define NUN 32    // NUNPAIRED
#define NM  480   // NMODES
#define NB  32    // BATCH
#define NF  288   // NE + NUN  (Ffull dim)
#define K0  168   // switch point: trailing 120x120 goes to LDS
#define N2  120   // NF - K0
#define SP  124   // LDS row pitch for phase 2 (floats, 16B-aligned)

typedef unsigned long long ull;

__device__ __forceinline__ float pick4(float4 a, int off) {
  return off == 0 ? a.x : off == 1 ? a.y : off == 2 ? a.z : a.w;
}

// ---------------- Ja = (J - J^T)/2 ----------------
__global__ __launch_bounds__(256)
void build_ja_k(const float* __restrict__ J, float* __restrict__ Ja) {
  int t = blockIdx.x * blockDim.x + threadIdx.x;
  int stride = gridDim.x * blockDim.x;
  for (int e = t; e < NM * NM; e += stride) {
    int i = e / NM, j = e - i * NM;
    Ja[e] = 0.5f * (J[i * NM + j] - J[j * NM + i]);
  }
}

// ---------------- Tmp[b] (256x480) = Up_b @ Ja ----------
__global__ __launch_bounds__(256)
void gemm1_k(const float* __restrict__ U, const int* __restrict__ idx,
             const float* __restrict__ Ja, float* __restrict__ Tmp) {
  const int b  = blockIdx.z;
  const int m0 = blockIdx.y << 6;
  const int n0 = blockIdx.x << 6;
  const int tid = threadIdx.x;
  __shared__ float As[16][64];
  __shared__ float Bs[16][64];
  const int ar = tid >> 2, ac = (tid & 3) << 2;
  const int br = tid >> 4, bc = (tid & 15) << 2;
  const int tx = tid & 15, ty = tid >> 4;
  const float* Arow = U + (size_t)idx[b * NE + m0 + ar] * NFM + NUN;
  float acc[4][4] = {};
  for (int l0 = 0; l0 < NM; l0 += 16) {
    float4 av = *(const float4*)(Arow + l0 + ac);
    As[ac + 0][ar] = av.x; As[ac + 1][ar] = av.y;
    As[ac + 2][ar] = av.z; As[ac + 3][ar] = av.w;
    float4 bv = make_float4(0.f, 0.f, 0.f, 0.f);
    if (n0 + bc < NM) bv = *(const float4*)(Ja + (size_t)(l0 + br) * NM + n0 + bc);
    *(float4*)(&Bs[br][bc]) = bv;
    __syncthreads();
#pragma unroll
    for (int kk = 0; kk < 16; ++kk) {
      float4 a4 = *(const float4*)(&As[kk][ty << 2]);
      float4 b4 = *(const float4*)(&Bs[kk][tx << 2]);
      float a[4] = {a4.x, a4.y, a4.z, a4.w};
      float bb[4] = {b4.x, b4.y, b4.z, b4.w};
#pragma unroll
      for (int q = 0; q < 4; ++q)
#pragma unroll
        for (int p = 0; p < 4; ++p) acc[q][p] = fmaf(a[q], bb[p], acc[q][p]);
    }
    __syncthreads();
  }
  float* Tb = Tmp + (size_t)b * NE * NM;
#pragma unroll
  for (int q = 0; q < 4; ++q) {
    int r = m0 + (ty << 2) + q;
#pragma unroll
    for (int p = 0; p < 4; ++p) {
      int m = n0 + (tx << 2) + p;
      if (m < NM) Tb[(size_t)r * NM + m] = acc[q][p];
    }
  }
}

// ---------------- F[b] = Tmp[b] @ Up_b^T  -> Ffull[0:256][0:256] ------------
__global__ __launch_bounds__(256)
void gemm2_k(const float* __restrict__ U, const int* __restrict__ idx,
             const float* __restrict__ Tmp, float* __restrict__ Ff) {
  const int b  = blockIdx.z;
  const int m0 = blockIdx.y << 6;
  const int n0 = blockIdx.x << 6;
  const int tid = threadIdx.x;
  __shared__ float As[16][64];
  __shared__ float Bs[16][64];
  const int ar = tid >> 2, ac = (tid & 3) << 2;
  const int jr = tid >> 2, kc = (tid & 3) << 2;
  const int tx = tid & 15, ty = tid >> 4;
  const float* Arow = Tmp + ((size_t)b * NE + m0 + ar) * NM;
  const float* Brow = U + (size_t)idx[b * NE + n0 + jr] * NFM + NUN;
  float acc[4][4] = {};
  for (int l0 = 0; l0 < NM; l0 += 16) {
    float4 av = *(const float4*)(Arow + l0 + ac);
    As[ac + 0][ar] = av.x; As[ac + 1][ar] = av.y;
    As[ac + 2][ar] = av.z; As[ac + 3][ar] = av.w;
    float4 bv = *(const float4*)(Brow + l0 + kc);
    Bs[kc + 0][jr] = bv.x; Bs[kc + 1][jr] = bv.y;
    Bs[kc + 2][jr] = bv.z; Bs[kc + 3][jr] = bv.w;
    __syncthreads();
#pragma unroll
    for (int kk = 0; kk < 16; ++kk) {
      float4 a4 = *(const float4*)(&As[kk][ty << 2]);
      float4 b4 = *(const float4*)(&Bs[kk][tx << 2]);
      float a[4] = {a4.x, a4.y, a4.z, a4.w};
      float bb[4] = {b4.x, b4.y, b4.z, b4.w};
#pragma unroll
      for (int q = 0; q < 4; ++q)
#pragma unroll
        for (int p = 0; p < 4; ++p) acc[q][p] = fmaf(a[q], bb[p], acc[q][p]);
    }
    __syncthreads();
  }
  float* Fb = Ff + (size_t)b * NF * NF;
#pragma unroll
  for (int q = 0; q < 4; ++q) {
    int i = m0 + (ty << 2) + q;
#pragma unroll
    for (int p = 0; p < 4; ++p) {
      int j = n0 + (tx << 2) + p;
      Fb[(size_t)i * NF + j] = acc[q][p];
    }
  }
}

// ---------------- edges ---------------
__global__ __launch_bounds__(256)
void fill_edges_k(const float* __restrict__ U, const int* __restrict__ idx,
                  float* __restrict__ Ff) {
  const int b = blockIdx.x;
  const int tid = threadIdx.x;
  float* Fb = Ff + (size_t)b * NF * NF;
  const int gr = idx[b * NE + tid];
#pragma unroll 4
  for (int u = 0; u < NUN; ++u) {
    float v = U[(size_t)gr * NFM + u];
    Fb[(size_t)tid * NF + NE + u] = v;
    Fb[(size_t)(NE + u) * NF + tid] = -v;
  }
  if (tid < NUN) {
    for (int v = 0; v < NUN; ++v) Fb[(size_t)(NE + tid) * NF + NE + v] = 0.f;
  }
}

// ---------------- Pfaffian phase 1: k = 0..K0-2 in global memory ------------
// 2 barriers/step, fused next-column argmax, lazy half-swap, batched float4 RMW
__global__ __launch_bounds__(512)
void pf1_k(float* __restrict__ Ff, float* __restrict__ state) {
  const int b = blockIdx.x;
  float* A = Ff + (size_t)b * NF * NF;
  const int tid = threadIdx.x;
  const int tx = tid & 63, ty = tid >> 6;
  __shared__ __align__(16) float s_tau[NF];
  __shared__ __align__(16) float s_c[NF];
  __shared__ ull s_pk[2];

  float sign = 1.f, logabs = 0.f;   // thread 0 only

  // bootstrap argmax for k=0 over column 0, rows 1..NF-1
  if (tid == 0) { s_pk[0] = 0; s_pk[1] = 0; }
  __syncthreads();
  if (tid < NF - 1) {
    int i = 1 + tid;
    unsigned bb = __float_as_uint(fabsf(A[(size_t)i * NF]));
    atomicMax(&s_pk[0], ((ull)bb << 32) | (ull)(NF - i));
  }
  __syncthreads();

  int p = 0;
  for (int k = 0; k < K0; k += 2) {
    const int np = p ^ 1;
    // ---------- staging: kp, pivot, tau/c, lazy half-swap ----------
    ull pk = s_pk[p];
    int kp = (pk >> 32) == 0 ? (k + 1) : (NF - (int)(pk & 0xffffffffULL));
    float piv = A[(size_t)k * NF + kp];
    if (tid == 0) {
      if (kp != k + 1) sign = -sign;
      sign *= (piv > 0.f ? 1.f : (piv < 0.f ? -1.f : 0.f));
      logabs += logf(fabsf(piv));
      s_pk[np] = 0;
    }
    const float invp = 1.f / piv;
    const bool swp = (kp != k + 1);
    const int rem = NF - (k + 2);
    if (tid < rem) {
      int i = k + 2 + tid;
      float rowk  = A[(size_t)k * NF + i];
      float colk1 = A[(size_t)i * NF + (k + 1)];
      float colkp = swp ? A[(size_t)i * NF + kp] : colk1;
      float tv, cv;
      if (swp && i == kp) { tv = A[(size_t)k * NF + (k + 1)] * invp; cv = -colk1; }
      else                { tv = rowk * invp;                        cv = colkp; }
      s_tau[i] = tv; s_c[i] = cv;
      if (swp) {
        A[(size_t)i * NF + kp] = (i == kp) ? 0.f : colk1;
        A[(size_t)kp * NF + i] = (i == kp) ? 0.f : -colk1;
      }
    }
    const int jlo = (k + 2) & ~3;
    if (tid < 4) {
      int j = jlo + tid;
      if (j < k + 2) { s_tau[j] = 0.f; s_c[j] = 0.f; }
    }
    __syncthreads();

    // ---------- trailing update (batched float4) + fused argmax col k+2 -----
    const int nch = (NF - jlo) >> 2;
    const int knext = k + 2;
    const int off = knext - jlo;
    ull lmax = 0;
    for (int i0 = k + 2 + ty; i0 < NF; i0 += 32) {
      const int i1 = i0 + 8, i2 = i0 + 16, i3 = i0 + 24;
      const bool v1 = i1 < NF, v2 = i2 < NF, v3 = i3 < NF;
      const int ii1 = v1 ? i1 : i0, ii2 = v2 ? i2 : i0, ii3 = v3 ? i3 : i0;
      const float t0 = s_tau[i0], c0 = s_c[i0];
      const float t1 = s_tau[ii1], c1 = s_c[ii1];
      const float t2 = s_tau[ii2], c2 = s_c[ii2];
      const float t3 = s_tau[ii3], c3 = s_c[ii3];
      float* r0 = A + (size_t)i0 * NF;
      float* r1 = A + (size_t)ii1 * NF;
      float* r2 = A + (size_t)ii2 * NF;
      float* r3 = A + (size_t)ii3 * NF;
      for (int j4 = tx; j4 < nch; j4 += 64) {
        const int j = jlo + (j4 << 2);
        float4 a0 = *(float4*)(r0 + j);
        float4 a1 = *(float4*)(r1 + j);
        float4 a2 = *(float4*)(r2 + j);
        float4 a3 = *(float4*)(r3 + j);
        const float4 cj = *(const float4*)(&s_c[j]);
        const float4 tj = *(const float4*)(&s_tau[j]);
        a0.x = fmaf(t0, cj.x, fmaf(-c0, tj.x, a0.x));
        a0.y = fmaf(t0, cj.y, fmaf(-c0, tj.y, a0.y));
        a0.z = fmaf(t0, cj.z, fmaf(-c0, tj.z, a0.z));
        a0.w = fmaf(t0, cj.w, fmaf(-c0, tj.w, a0.w));
        a1.x = fmaf(t1, cj.x, fmaf(-c1, tj.x, a1.x));
        a1.y = fmaf(t1, cj.y, fmaf(-c1, tj.y, a1.y));
        a1.z = fmaf(t1, cj.z, fmaf(-c1, tj.z, a1.z));
        a1.w = fmaf(t1, cj.w, fmaf(-c1, tj.w, a1.w));
        a2.x = fmaf(t2, cj.x, fmaf(-c2, tj.x, a2.x));
        a2.y = fmaf(t2, cj.y, fmaf(-c2, tj.y, a2.y));
        a2.z = fmaf(t2, cj.z, fmaf(-c2, tj.z, a2.z));
        a2.w = fmaf(t2, cj.w, fmaf(-c2, tj.w, a2.w));
        a3.x = fmaf(t3, cj.x, fmaf(-c3, tj.x, a3.x));
        a3.y = fmaf(t3, cj.y, fmaf(-c3, tj.y, a3.y));
        a3.z = fmaf(t3, cj.z, fmaf(-c3, tj.z, a3.z));
        a3.w = fmaf(t3, cj.w, fmaf(-c3, tj.w, a3.w));
        *(float4*)(r0 + j) = a0;
        if (v1) *(float4*)(r1 + j) = a1;
        if (v2) *(float4*)(r2 + j) = a2;
        if (v3) *(float4*)(r3 + j) = a3;
        if (j4 == 0) {  // fused argmax for next step's pivot column (k+2)
          if (i0 > knext) {
            unsigned bb = __float_as_uint(fabsf(pick4(a0, off)));
            ull pkv = ((ull)bb << 32) | (ull)(NF - i0);
            lmax = lmax < pkv ? pkv : lmax;
          }
          if (v1) { unsigned bb = __float_as_uint(fabsf(pick4(a1, off)));
                    ull pkv = ((ull)bb << 32) | (ull)(NF - i1);
                    lmax = lmax < pkv ? pkv : lmax; }
          if (v2) { unsigned bb = __float_as_uint(fabsf(pick4(a2, off)));
                    ull pkv = ((ull)bb << 32) | (ull)(NF - i2);
                    lmax = lmax < pkv ? pkv : lmax; }
          if (v3) { unsigned bb = __float_as_uint(fabsf(pick4(a3, off)));
                    ull pkv = ((ull)bb << 32) | (ull)(NF - i3);
                    lmax = lmax < pkv ? pkv : lmax; }
        }
      }
    }
    if (tx == 0 && lmax) atomicMax(&s_pk[np], lmax);
    __syncthreads();
    p = np;
  }

  if (tid == 0) { state[2 * b] = sign; state[2 * b + 1] = logabs; }
}

// ---------------- Pfaffian phase 2: trailing 120x120 entirely in LDS --------
__global__ __launch_bounds__(512)
void pf2_k(const float* __restrict__ Ff, const float* __restrict__ state,
           float* __restrict__ out) {
  const int b = blockIdx.x;
  const float* A = Ff + (size_t)b * NF * NF;
  const int tid = threadIdx.x;
  __shared__ __align__(16) float sA[N2 * SP];
  __shared__ __align__(16) float s_tau[N2];
  __shared__ __align__(16) float s_c[N2];
  __shared__ ull s_pk;

  // load trailing block [K0..NF) x [K0..NF) into LDS
  for (int e = tid; e < N2 * (N2 / 4); e += 512) {
    int r = e / (N2 / 4), c4 = e - r * (N2 / 4);
    float4 v = *(const float4*)(A + (size_t)(K0 + r) * NF + K0 + (c4 << 2));
    *(float4*)(&sA[r * SP + (c4 << 2)]) = v;
  }
  if (tid == 0) s_pk = 0;
  __syncthreads();

  float sign = 1.f, logabs = 0.f;
  if (tid == 0) { sign = state[2 * b]; logabs = state[2 * b + 1]; }

  for (int kl = 0; kl < N2 - 1; kl += 2) {
    // ---- argmax over column kl, rows > kl ----
    const int remc = N2 - (kl + 1);
    if (tid < remc) {
      int i = kl + 1 + tid;
      unsigned bb = __float_as_uint(fabsf(sA[i * SP + kl]));
      atomicMax(&s_pk, ((ull)bb << 32) | (ull)(N2 - i));
    }
    __syncthreads();

    // ---- staging ----
    ull pk = s_pk;
    int kp = (pk >> 32) == 0 ? (kl + 1) : (N2 - (int)(pk & 0xffffffffULL));
    float piv = sA[kl * SP + kp];
    if (tid == 0) {
      if (kp != kl + 1) sign = -sign;
      sign *= (piv > 0.f ? 1.f : (piv < 0.f ? -1.f : 0.f));
      logabs += logf(fabsf(piv));
    }
    const float invp = 1.f / piv;
    const bool swp = (kp != kl + 1);
    const int rem = N2 - (kl + 2);
    if (tid < rem) {
      int i = kl + 2 + tid;
      float rowk  = sA[kl * SP + i];
      float colk1 = sA[i * SP + (kl + 1)];
      float colkp = swp ? sA[i * SP + kp] : colk1;
      float tv, cv;
      if (swp && i == kp) { tv = sA[kl * SP + (kl + 1)] * invp; cv = -colk1; }
      else                { tv = rowk * invp;                   cv = colkp; }
      s_tau[i] = tv; s_c[i] = cv;
      if (swp) {
        sA[i * SP + kp] = (i == kp) ? 0.f : colk1;
        sA[kp * SP + i] = (i == kp) ? 0.f : -colk1;
      }
    }
    const int jlo = (kl + 2) & ~3;
    if (tid < 4) {
      int j = jlo + tid;
      if (j < kl + 2) { s_tau[j] = 0.f; s_c[j] = 0.f; }
    }
    __syncthreads();

    // ---- trailing update in LDS ----
    const int nch = (N2 - jlo) >> 2;
    const int c4 = tid & 31, rr = tid >> 5;  // 32 col-chunks x 16 row streams
    if (c4 < nch) {
      const int j = jlo + (c4 << 2);
      const float4 cj = *(const float4*)(&s_c[j]);
      const float4 tj = *(const float4*)(&s_tau[j]);
      for (int i = kl + 2 + rr; i < N2; i += 16) {
        const float ti = s_tau[i], ci = s_c[i];
        float4 a = *(float4*)(&sA[i * SP + j]);
        a.x = fmaf(ti, cj.x, fmaf(-ci, tj.x, a.x));
        a.y = fmaf(ti, cj.y, fmaf(-ci, tj.y, a.y));
        a.z = fmaf(ti, cj.z, fmaf(-ci, tj.z, a.z));
        a.w = fmaf(ti, cj.w, fmaf(-ci, tj.w, a.w));
        *(float4*)(&sA[i * SP + j]) = a;
      }
    }
    if (tid == 0) s_pk = 0;   // reset for next step's argmax
    __syncthreads();
  }

  if (tid == 0) { out[b] = sign; out[NB + b] = logabs; }
}

extern "C" void kernel_launch(void* const* d_in, const int* in_sizes, int n_in,
                              void* d_out, int out_size, void* d_ws, size_t ws_size,
                              hipStream_t stream) {
  const float* U  = (const float*)d_in[0];
  const float* J  = (const float*)d_in[1];
  const int* idx  = (const int*)d_in[2];
  float* out = (float*)d_out;
  float* ws = (float*)d_ws;

  float* Ja  = ws;                          // 480*480
  float* Tmp = Ja + (size_t)NM * NM;        // 32*256*480
  float* Ff  = Tmp + (size_t)NB * NE * NM;  // 32*288*288
  float* state = Tmp;                       // Tmp is dead after gemm2; reuse

  build_ja_k<<<dim3(256), dim3(256), 0, stream>>>(J, Ja);
  gemm1_k<<<dim3(8, 4, NB), dim3(256), 0, stream>>>(U, idx, Ja, Tmp);
  gemm2_k<<<dim3(4, 4, NB), dim3(256), 0, stream>>>(U, idx, Tmp, Ff);
  fill_edges_k<<<dim3(NB), dim3(256), 0, stream>>>(U, idx, Ff);
  pf1_k<<<dim3(NB), dim3(512), 0, stream>>>(Ff, state);
  pf2_k<<<dim3(NB), dim3(512), 0, stream>>>(Ff, state, out);
}

// Round 3
// 533.845 us; speedup vs baseline: 3.2760x; 1.5770x over previous
//
#include <hip/hip_runtime.h>
#include <hip/hip_bf16.h>
#include <math.h>

#define NFM 512   // NFMODES
#define NE  256
#define NUN 32    // NUNPAIRED
#define NM  480   // NMODES
#define NB  32    // BATCH
#define NF  288   // NE + NUN  (Ffull dim)
#define WP  16    // panel width (columns)
#define PAIRS 8   // WP/2 (tau,c) pairs per panel
#define PPITCH 17 // LDS pitch for panel (odd -> conflict-free strided access)

typedef unsigned long long ull;

// ---------------- Ja = (J - J^T)/2 ----------------
__global__ __launch_bounds__(256)
void build_ja_k(const float* __restrict__ J, float* __restrict__ Ja) {
  int t = blockIdx.x * blockDim.x + threadIdx.x;
  int stride = gridDim.x * blockDim.x;
  for (int e = t; e < NM * NM; e += stride) {
    int i = e / NM, j = e - i * NM;
    Ja[e] = 0.5f * (J[i * NM + j] - J[j * NM + i]);
  }
}

// ---------------- Tmp[b] (256x480) = Up_b @ Ja ----------
__global__ __launch_bounds__(256)
void gemm1_k(const float* __restrict__ U, const int* __restrict__ idx,
             const float* __restrict__ Ja, float* __restrict__ Tmp) {
  const int b  = blockIdx.z;
  const int m0 = blockIdx.y << 6;
  const int n0 = blockIdx.x << 6;
  const int tid = threadIdx.x;
  __shared__ float As[16][64];
  __shared__ float Bs[16][64];
  const int ar = tid >> 2, ac = (tid & 3) << 2;
  const int br = tid >> 4, bc = (tid & 15) << 2;
  const int tx = tid & 15, ty = tid >> 4;
  const float* Arow = U + (size_t)idx[b * NE + m0 + ar] * NFM + NUN;
  float acc[4][4] = {};
  for (int l0 = 0; l0 < NM; l0 += 16) {
    float4 av = *(const float4*)(Arow + l0 + ac);
    As[ac + 0][ar] = av.x; As[ac + 1][ar] = av.y;
    As[ac + 2][ar] = av.z; As[ac + 3][ar] = av.w;
    float4 bv = make_float4(0.f, 0.f, 0.f, 0.f);
    if (n0 + bc < NM) bv = *(const float4*)(Ja + (size_t)(l0 + br) * NM + n0 + bc);
    *(float4*)(&Bs[br][bc]) = bv;
    __syncthreads();
#pragma unroll
    for (int kk = 0; kk < 16; ++kk) {
      float4 a4 = *(const float4*)(&As[kk][ty << 2]);
      float4 b4 = *(const float4*)(&Bs[kk][tx << 2]);
      float a[4] = {a4.x, a4.y, a4.z, a4.w};
      float bb[4] = {b4.x, b4.y, b4.z, b4.w};
#pragma unroll
      for (int q = 0; q < 4; ++q)
#pragma unroll
        for (int p = 0; p < 4; ++p) acc[q][p] = fmaf(a[q], bb[p], acc[q][p]);
    }
    __syncthreads();
  }
  float* Tb = Tmp + (size_t)b * NE * NM;
#pragma unroll
  for (int q = 0; q < 4; ++q) {
    int r = m0 + (ty << 2) + q;
#pragma unroll
    for (int p = 0; p < 4; ++p) {
      int m = n0 + (tx << 2) + p;
      if (m < NM) Tb[(size_t)r * NM + m] = acc[q][p];
    }
  }
}

// ---------------- F[b] = Tmp[b] @ Up_b^T  -> Ffull[0:256][0:256] ------------
__global__ __launch_bounds__(256)
void gemm2_k(const float* __restrict__ U, const int* __restrict__ idx,
             const float* __restrict__ Tmp, float* __restrict__ Ff) {
  const int b  = blockIdx.z;
  const int m0 = blockIdx.y << 6;
  const int n0 = blockIdx.x << 6;
  const int tid = threadIdx.x;
  __shared__ float As[16][64];
  __shared__ float Bs[16][64];
  const int ar = tid >> 2, ac = (tid & 3) << 2;
  const int jr = tid >> 2, kc = (tid & 3) << 2;
  const int tx = tid & 15, ty = tid >> 4;
  const float* Arow = Tmp + ((size_t)b * NE + m0 + ar) * NM;
  const float* Brow = U + (size_t)idx[b * NE + n0 + jr] * NFM + NUN;
  float acc[4][4] = {};
  for (int l0 = 0; l0 < NM; l0 += 16) {
    float4 av = *(const float4*)(Arow + l0 + ac);
    As[ac + 0][ar] = av.x; As[ac + 1][ar] = av.y;
    As[ac + 2][ar] = av.z; As[ac + 3][ar] = av.w;
    float4 bv = *(const float4*)(Brow + l0 + kc);
    Bs[kc + 0][jr] = bv.x; Bs[kc + 1][jr] = bv.y;
    Bs[kc + 2][jr] = bv.z; Bs[kc + 3][jr] = bv.w;
    __syncthreads();
#pragma unroll
    for (int kk = 0; kk < 16; ++kk) {
      float4 a4 = *(const float4*)(&As[kk][ty << 2]);
      float4 b4 = *(const float4*)(&Bs[kk][tx << 2]);
      float a[4] = {a4.x, a4.y, a4.z, a4.w};
      float bb[4] = {b4.x, b4.y, b4.z, b4.w};
#pragma unroll
      for (int q = 0; q < 4; ++q)
#pragma unroll
        for (int p = 0; p < 4; ++p) acc[q][p] = fmaf(a[q], bb[p], acc[q][p]);
    }
    __syncthreads();
  }
  float* Fb = Ff + (size_t)b * NF * NF;
#pragma unroll
  for (int q = 0; q < 4; ++q) {
    int i = m0 + (ty << 2) + q;
#pragma unroll
    for (int p = 0; p < 4; ++p) {
      int j = n0 + (tx << 2) + p;
      Fb[(size_t)i * NF + j] = acc[q][p];
    }
  }
}

// ---------------- edges ---------------
__global__ __launch_bounds__(256)
void fill_edges_k(const float* __restrict__ U, const int* __restrict__ idx,
                  float* __restrict__ Ff) {
  const int b = blockIdx.x;
  const int tid = threadIdx.x;
  float* Fb = Ff + (size_t)b * NF * NF;
  const int gr = idx[b * NE + tid];
#pragma unroll 4
  for (int u = 0; u < NUN; ++u) {
    float v = U[(size_t)gr * NFM + u];
    Fb[(size_t)tid * NF + NE + u] = v;
    Fb[(size_t)(NE + u) * NF + tid] = -v;
  }
  if (tid < NUN) {
    for (int v = 0; v < NUN; ++v) Fb[(size_t)(NE + tid) * NF + NE + v] = 0.f;
  }
}

// ---------------- Pfaffian: blocked Parlett-Reid, panel in LDS --------------
// Invariant: A_cur[i][j] = snap[i][j] + sum_m (tau_m[i]c_m[j] - c_m[i]tau_m[j])
// where snap lives in P (panel cols, all rows) + global A (trailing cols).
// Swaps transform snapshot + (tau,c) entries; trailing rank-2*PAIRS update is
// applied once per panel as a streaming pass.
__global__ __launch_bounds__(512)
void pfpanel_k(float* __restrict__ Ff, float* __restrict__ out) {
  const int b = blockIdx.x;
  float* A = Ff + (size_t)b * NF * NF;
  const int tid = threadIdx.x;
  __shared__ __align__(16) float P[NF * PPITCH];
  __shared__ __align__(16) float s_tau[PAIRS][NF];
  __shared__ __align__(16) float s_c[PAIRS][NF];
  __shared__ __align__(16) float s_colbuf[NF];
  __shared__ __align__(16) float s_coltmp[NF];
  __shared__ float s_rowtmp[WP];
  __shared__ ull s_red[8];

  float sign = 1.f, logabs = 0.f;  // thread 0 only

  for (int k0 = 0; k0 < NF; k0 += WP) {
    const int pend = k0 + WP;

    // ---- panel load: P[i][lc] = A[i][k0+lc], one 64B row-slice per thread --
    if (tid < NF) {
      const float* src = A + (size_t)tid * NF + k0;
      float* dst = P + tid * PPITCH;
      float4 v0 = *(const float4*)(src + 0);
      float4 v1 = *(const float4*)(src + 4);
      float4 v2 = *(const float4*)(src + 8);
      float4 v3 = *(const float4*)(src + 12);
      dst[0] = v0.x;  dst[1] = v0.y;  dst[2] = v0.z;  dst[3] = v0.w;
      dst[4] = v1.x;  dst[5] = v1.y;  dst[6] = v1.z;  dst[7] = v1.w;
      dst[8] = v2.x;  dst[9] = v2.y;  dst[10] = v2.z; dst[11] = v2.w;
      dst[12] = v3.x; dst[13] = v3.y; dst[14] = v3.z; dst[15] = v3.w;
    }
    __syncthreads();

    for (int mp = 0; mp < PAIRS; ++mp) {
      const int k = k0 + 2 * mp;
      const int lc = 2 * mp;
      const int lc1 = lc + 1;

      // ---- phase 1: current column k + argmax (shfl butterfly) ----
      ull pk = 0;
      if (tid > k && tid < NF) {
        float v = P[tid * PPITCH + lc];
        for (int m = 0; m < mp; ++m)
          v = fmaf(s_tau[m][tid], s_c[m][k], fmaf(-s_c[m][tid], s_tau[m][k], v));
        s_colbuf[tid] = v;
        pk = ((ull)__float_as_uint(fabsf(v)) << 32) | (ull)(NF - tid);
      }
#pragma unroll
      for (int m = 32; m > 0; m >>= 1) {
        ull o = __shfl_xor(pk, m, 64);
        if (o > pk) pk = o;
      }
      if ((tid & 63) == 0) s_red[tid >> 6] = pk;
      __syncthreads();
      ull best = s_red[0];
#pragma unroll
      for (int w = 1; w < 8; ++w) if (s_red[w] > best) best = s_red[w];
      const int kp = NF - (int)(best & 0xffffffffULL);
      const float pivot = -s_colbuf[kp];
      const float invp = 1.f / pivot;
      if (tid == 0) {
        if (kp != k + 1) sign = -sign;
        sign *= (pivot > 0.f ? 1.f : (pivot < 0.f ? -1.f : 0.f));
        logabs += logf(fabsf(pivot));
      }

      // ---- phase 2: apply transposition (k+1 <-> kp) to snapshot ----
      if (kp != k + 1) {
        if (kp < pend) {
          // 2a: P row swap (reg temp per column) + tau/c entry swaps
          if (tid < WP) {
            float ta = P[(k + 1) * PPITCH + tid];
            P[(k + 1) * PPITCH + tid] = P[kp * PPITCH + tid];
            P[kp * PPITCH + tid] = ta;
          } else if (tid >= 304 && tid < 320) {
            int t2 = tid - 304, m = t2 & 7;
            if (m < mp) {
              float* vv = (t2 < 8) ? &s_tau[m][0] : &s_c[m][0];
              float tt = vv[k + 1]; vv[k + 1] = vv[kp]; vv[kp] = tt;
            }
          }
          __syncthreads();
          // 2b: P column swap lc1 <-> lckp (same-thread pair)
          const int lckp = kp - k0;
          if (tid < NF) {
            float* pr = P + tid * PPITCH;
            float ta = pr[lc1]; pr[lc1] = pr[lckp]; pr[lckp] = ta;
          }
          __syncthreads();
        } else {
          // 2a: global row/col kp fix (corrections cancel exactly),
          //     stage old P row kp and old global col kp; tau/c swaps
          if (tid < NF) {
            if (tid >= pend) {
              int j = tid;
              if (j == kp) {
                s_coltmp[kp] = -P[kp * PPITCH + lc1];
                A[(size_t)kp * NF + kp] = 0.f;
              } else {
                float pv = P[j * PPITCH + lc1];
                float gv = A[(size_t)j * NF + kp];
                A[(size_t)kp * NF + j] = -pv;
                A[(size_t)j * NF + kp] = pv;
                s_coltmp[j] = gv;
              }
            }
          } else if (tid >= 288 && tid < 288 + WP) {
            s_rowtmp[tid - 288] = P[kp * PPITCH + (tid - 288)];
          } else if (tid >= 304 && tid < 320) {
            int t2 = tid - 304, m = t2 & 7;
            if (m < mp) {
              float* vv = (t2 < 8) ? &s_tau[m][0] : &s_c[m][0];
              float tt = vv[k + 1]; vv[k + 1] = vv[kp]; vv[kp] = tt;
            }
          }
          __syncthreads();
          // 2b: P row swap (skip col lc1) + rebuild P column lc1
          if (tid >= 320 && tid < 320 + WP) {
            int t = tid - 320;
            if (t != lc1) {
              float oldk1 = P[(k + 1) * PPITCH + t];
              P[(k + 1) * PPITCH + t] = s_rowtmp[t];
              P[kp * PPITCH + t] = oldk1;
            }
          } else if (tid < NF) {
            int i = tid;
            float nv;
            if (i == k + 1)      nv = 0.f;
            else if (i == kp)    nv = -s_rowtmp[lc1];
            else if (i >= pend)  nv = s_coltmp[i];
            else if (i >= k0)    nv = -s_rowtmp[i - k0];
            else                 nv = 0.f;
            P[i * PPITCH + lc1] = nv;
          }
          __syncthreads();
        }
      }

      // ---- phase 3: stage pair (tau, c) ----
      {
        float tv = 0.f, cv = 0.f;
        if (tid > k + 1 && tid < NF) {
          float colpost = (tid == kp) ? s_colbuf[k + 1] : s_colbuf[tid];
          tv = -colpost * invp;
          cv = P[tid * PPITCH + lc1];
          for (int m = 0; m < mp; ++m)
            cv = fmaf(s_tau[m][tid], s_c[m][k + 1],
                      fmaf(-s_c[m][tid], s_tau[m][k + 1], cv));
        }
        if (tid < NF) { s_tau[mp][tid] = tv; s_c[mp][tid] = cv; }
      }
      __syncthreads();
    }

    // ---- panel-end: streaming rank-2*PAIRS update of trailing block --------
    if (pend < NF) {
      const int ty = tid >> 6, tx = tid & 63;
      const int nch = (NF - pend) >> 2;
      for (int i = pend + ty; i < NF; i += 8) {
        float ti[PAIRS], ci[PAIRS];
#pragma unroll
        for (int m = 0; m < PAIRS; ++m) { ti[m] = s_tau[m][i]; ci[m] = s_c[m][i]; }
        for (int j4 = tx; j4 < nch; j4 += 64) {
          const int j = pend + (j4 << 2);
          float* ap = A + (size_t)i * NF + j;
          float4 a = *(float4*)ap;
#pragma unroll
          for (int m = 0; m < PAIRS; ++m) {
            const float4 cj = *(const float4*)(&s_c[m][j]);
            const float4 tj = *(const float4*)(&s_tau[m][j]);
            a.x = fmaf(ti[m], cj.x, fmaf(-ci[m], tj.x, a.x));
            a.y = fmaf(ti[m], cj.y, fmaf(-ci[m], tj.y, a.y));
            a.z = fmaf(ti[m], cj.z, fmaf(-ci[m], tj.z, a.z));
            a.w = fmaf(ti[m], cj.w, fmaf(-ci[m], tj.w, a.w));
          }
          *(float4*)ap = a;
        }
      }
    }
    __syncthreads();
  }

  if (tid == 0) { out[b] = sign; out[NB + b] = logabs; }
}

extern "C" void kernel_launch(void* const* d_in, const int* in_sizes, int n_in,
                              void* d_out, int out_size, void* d_ws, size_t ws_size,
                              hipStream_t stream) {
  const float* U  = (const float*)d_in[0];
  const float* J  = (const float*)d_in[1];
  const int* idx  = (const int*)d_in[2];
  float* out = (float*)d_out;
  float* ws = (float*)d_ws;

  float* Ja  = ws;                          // 480*480
  float* Tmp = Ja + (size_t)NM * NM;        // 32*256*480
  float* Ff  = Tmp + (size_t)NB * NE * NM;  // 32*288*288

  build_ja_k<<<dim3(256), dim3(256), 0, stream>>>(J, Ja);
  gemm1_k<<<dim3(8, 4, NB), dim3(256), 0, stream>>>(U, idx, Ja, Tmp);
  gemm2_k<<<dim3(4, 4, NB), dim3(256), 0, stream>>>(U, idx, Tmp, Ff);
  fill_edges_k<<<dim3(NB), dim3(256), 0, stream>>>(U, idx, Ff);
  pfpanel_k<<<dim3(NB), dim3(512), 0, stream>>>(Ff, out);
}